// Round 1
// 257.965 us; speedup vs baseline: 1.3603x; 1.3603x over previous
//
#include <hip/hip_runtime.h>
#include <stdint.h>
#include <math.h>

// ---------------------------------------------------------------------------
// Generator_44555990728950. B=4096 molecules, N=32 nodes (chain), H=128,
// 16 GAT layers.
// R7 restructure: all 32 nodes of a molecule are IDENTICAL through the whole
// GAT stack (x starts as a broadcast of h0 and attention weights sum to 1 over
// identical neighbors => out == h to ~1e-16 in fp64). So:
//   - single class per molecule (was 2), attention math dropped entirely:
//     layer = relu(x + x@W + b)
//   - K-split across a wave pair (each wave does 64 of 128 k-terms for 2
//     molecules, partials combined via LDS + 2 barriers/layer)
//   - 4 mols/block -> 1024 blocks -> 4 blocks/CU -> 50% occupancy
//     (was 512 blocks / 23%: grid-limited, VALUBusy 37%)
// Deterministic pipeline fp64; JAX partitionable threefry bit-exact; outputs
// fp32. Per-node sampling / edge heads unchanged.
// ---------------------------------------------------------------------------

struct U2 { uint32_t a, b; };

// Threefry-2x32, 20 rounds, exactly as jax._src.prng
__device__ __forceinline__ U2 threefry(uint32_t k0, uint32_t k1, uint32_t x0, uint32_t x1) {
  const uint32_t ks2 = k0 ^ k1 ^ 0x1BD11BDAu;
#define TFR(r) { x0 += x1; x1 = (x1 << (r)) | (x1 >> (32 - (r))); x1 ^= x0; }
  x0 += k0;  x1 += k1;
  TFR(13) TFR(15) TFR(26) TFR(6)
  x0 += k1;  x1 += ks2 + 1u;
  TFR(17) TFR(29) TFR(16) TFR(24)
  x0 += ks2; x1 += k0 + 2u;
  TFR(13) TFR(15) TFR(26) TFR(6)
  x0 += k0;  x1 += k1 + 3u;
  TFR(17) TFR(29) TFR(16) TFR(24)
  x0 += k1;  x1 += ks2 + 4u;
  TFR(13) TFR(15) TFR(26) TFR(6)
  x0 += ks2; x1 += k0 + 5u;
#undef TFR
  U2 r; r.a = x0; r.b = x1; return r;
}

// partitionable random_bits, 32-bit: counter = flat index; fold o1^o2
__device__ __forceinline__ uint32_t pbits(uint32_t k0, uint32_t k1, uint32_t ctr) {
  U2 r = threefry(k0, k1, 0u, ctr);
  return r.a ^ r.b;
}

__device__ __forceinline__ float bits_to_unit(uint32_t bits) {
  return __uint_as_float((bits >> 9) | 0x3f800000u) - 1.0f;  // [0,1)
}

// f32 uniform(1e-6, 1-1e-6) -> gumbel, exactly jax's f32 path
__device__ __forceinline__ float jgumbel(uint32_t k0, uint32_t k1, uint32_t ctr) {
  const float minv = 1e-6f;
  const float maxv = (float)(1.0 - 1e-6);
  const float span = maxv - minv;
  float f = bits_to_unit(pbits(k0, k1, ctr));
  float u = fmaxf(minv, __fadd_rn(__fmul_rn(f, span), minv));
  return -logf(-logf(u));
}

extern "C" __global__ void __launch_bounds__(256, 4)
gen_kernel(const float* __restrict__ noise,
           const float* __restrict__ w1,
           const float* __restrict__ b1,
           const float* __restrict__ gat_w,
           const float* __restrict__ gat_b,
           const float* __restrict__ att_src,
           const float* __restrict__ att_dst,
           const float* __restrict__ w_atom,
           const float* __restrict__ b_atom,
           const float* __restrict__ w_hyb,
           const float* __restrict__ b_hyb,
           const float* __restrict__ w_deg,
           const float* __restrict__ b_deg,
           const float* __restrict__ w_chg,
           const float* __restrict__ b_chg,
           const float* __restrict__ w_arom,
           const float* __restrict__ b_arom,
           const float* __restrict__ w_eex,
           const float* __restrict__ b_eex,
           const float* __restrict__ w_ety,
           const float* __restrict__ b_ety,
           float* __restrict__ out)
{
  (void)att_src; (void)att_dst;   // attention is a no-op on identical nodes

  // Per block: 2 wave-pairs; each pair = 2 waves handling 2 molecules with a
  // k-split (wave wh owns k in [wh*64, wh*64+64)).
  __shared__ __align__(16) double sX[2][128][2];     // [pair][col][mol]  4 KB
  __shared__ __align__(16) double sRed[2][2][128];   // [pair][wave][col] 4 KB
  __shared__ double sScr[2][2][16];                  // head logits       512 B
  __shared__ float  sNF[2][2][32][17];               // node features     8.5 KB
  __shared__ double sLP[2][2][64];                   // lp scratch        2 KB

  const int t    = threadIdx.x;
  const int wv   = t >> 6;
  const int ln   = t & 63;
  const int pair = wv >> 1;
  const int wh   = wv & 1;                            // k-half AND mol-in-pair
  const int mol  = blockIdx.x * 4 + pair * 2 + wh;    // this wave's molecule
  const int c0   = ln << 1;                           // lane's two columns

  // ---------------- stage noise for own molecule into sX
  {
    const float2 nz = *(const float2*)(noise + (size_t)mol * 128 + c0);
    sX[pair][c0][wh]     = (double)nz.x;
    sX[pair][c0 + 1][wh] = (double)nz.y;
  }
  __syncthreads();

  // ---------------- phase 0: x0 = relu(noise @ w1 + b1), k-split matvec
  {
    const float*  Wk = w1 + (wh << 13);               // wh*64*128
    const double* xp = &sX[pair][wh << 6][0];
    double a0x = 0.0, a0y = 0.0, a1x = 0.0, a1y = 0.0;
    #pragma unroll 8
    for (int k = 0; k < 64; ++k) {
      const double2 X = *(const double2*)(xp + (k << 1));   // {x_m0, x_m1}
      const float2  w = *(const float2*)(Wk + (k << 7) + c0);
      const double wx = (double)w.x, wy = (double)w.y;
      a0x = fma(X.x, wx, a0x); a0y = fma(X.x, wy, a0y);
      a1x = fma(X.y, wx, a1x); a1y = fma(X.y, wy, a1y);
    }
    // write partials for the molecule the SIBLING finalizes
    double2 cw; cw.x = wh ? a0x : a1x; cw.y = wh ? a0y : a1y;
    *(double2*)&sRed[pair][wh][c0] = cw;
    __syncthreads();
    const double2 pp = *(const double2*)&sRed[pair][wh ^ 1][c0];
    const float2  bb = *(const float2*)(b1 + c0);
    const double hx = (wh ? a1x : a0x) + pp.x + (double)bb.x;
    const double hy = (wh ? a1y : a0y) + pp.y + (double)bb.y;
    sX[pair][c0][wh]     = fmax(hx, 0.0);
    sX[pair][c0 + 1][wh] = fmax(hy, 0.0);
    __syncthreads();
  }

  // ---------------- 16 layers: x = relu(x + x@W + b), k-split matvec
  for (int l = 0; l < 16; ++l) {
    const float*  Wk = gat_w + (size_t)l * 16384 + (wh << 13);
    const double* xp = &sX[pair][wh << 6][0];
    double a0x = 0.0, a0y = 0.0, a1x = 0.0, a1y = 0.0;
    #pragma unroll 8
    for (int k = 0; k < 64; ++k) {
      const double2 X = *(const double2*)(xp + (k << 1));
      const float2  w = *(const float2*)(Wk + (k << 7) + c0);
      const double wx = (double)w.x, wy = (double)w.y;
      a0x = fma(X.x, wx, a0x); a0y = fma(X.x, wy, a0y);
      a1x = fma(X.y, wx, a1x); a1y = fma(X.y, wy, a1y);
    }
    double2 cw; cw.x = wh ? a0x : a1x; cw.y = wh ? a0y : a1y;
    *(double2*)&sRed[pair][wh][c0] = cw;
    __syncthreads();                      // all k-loop reads of sX are done
    const double2 pp = *(const double2*)&sRed[pair][wh ^ 1][c0];
    const float2  bb = *(const float2*)(gat_b + l * 128 + c0);
    const double hx = (wh ? a1x : a0x) + pp.x + (double)bb.x;
    const double hy = (wh ? a1y : a0y) + pp.y + (double)bb.y;
    const double rx = sX[pair][c0][wh];
    const double ry = sX[pair][c0 + 1][wh];
    sX[pair][c0][wh]     = fmax(rx + hx, 0.0);
    sX[pair][c0 + 1][wh] = fmax(ry + hy, 0.0);
    __syncthreads();                      // new x visible to sibling wave
  }

  // ---------------- phase A: 16 head logits for own molecule (lanes 0..15)
  if (ln < 16) {
    const float* wp; int stride;
    if (ln < 10)      { wp = w_atom + ln;        stride = 10; }
    else if (ln < 13) { wp = w_hyb + (ln - 10);  stride = 3;  }
    else if (ln == 13){ wp = w_deg;              stride = 1;  }
    else if (ln == 14){ wp = w_chg;              stride = 1;  }
    else              { wp = w_arom;             stride = 1;  }
    double acc = 0.0;
    for (int c = 0; c < 128; ++c)
      acc = fma(sX[pair][c][wh], (double)wp[c * stride], acc);
    double bias;
    if (ln < 10)      bias = (double)b_atom[ln];
    else if (ln < 13) bias = (double)b_hyb[ln - 10];
    else if (ln == 13)bias = (double)b_deg[0];
    else if (ln == 14)bias = (double)b_chg[0];
    else              bias = (double)b_arom[0];
    sScr[pair][wh][ln] = acc + bias;
  }

  // partitionable split(key(42),4): child_i = threefry((0,42),(0,i))
  const U2 k0p = threefry(0u, 42u, 0u, 0u);
  const U2 k1p = threefry(0u, 42u, 0u, 1u);
  const U2 k2p = threefry(0u, 42u, 0u, 2u);
  const U2 k3p = threefry(0u, 42u, 0u, 3u);

  // ---------------- phase B: per-node sampling (lanes 0..31 = 32 nodes)
  if (ln < 32) {
    const int n = ln;
    const double* scr = sScr[pair][wh];   // same logits for every node

    double m = scr[0];
    #pragma unroll
    for (int a = 1; a < 10; ++a) m = fmax(m, scr[a]);
    double lsum = 0.0;
    #pragma unroll
    for (int a = 0; a < 10; ++a) lsum += exp(scr[a] - m);
    const double lse = log(lsum);
    const uint32_t abase = ((uint32_t)mol * 32u + (uint32_t)n) * 10u;
    int asel = 0; double abest = 0.0;
    #pragma unroll
    for (int a = 0; a < 10; ++a) {
      const double g = (double)jgumbel(k0p.a, k0p.b, abase + (uint32_t)a);
      const double sc = scr[a] + g;
      if (a == 0 || sc > abest) { abest = sc; asel = a; }
    }
    sLP[pair][wh][n] = (scr[asel] - m) - lse;

    double m2 = fmax(fmax(scr[10], scr[11]), scr[12]);
    double ls2 = exp(scr[10] - m2) + exp(scr[11] - m2) + exp(scr[12] - m2);
    const double lse2 = log(ls2);
    const uint32_t hbase = ((uint32_t)mol * 32u + (uint32_t)n) * 3u;
    int hsel = 0; double hbest = 0.0;
    #pragma unroll
    for (int j = 0; j < 3; ++j) {
      const double g = (double)jgumbel(k1p.a, k1p.b, hbase + (uint32_t)j);
      const double sc = scr[10 + j] + g;
      if (j == 0 || sc > hbest) { hbest = sc; hsel = j; }
    }
    sLP[pair][wh][32 + n] = (scr[10 + hsel] - m2) - lse2;

    const double deg = 1.0 / (1.0 + exp(-scr[13]));
    const double chg = tanh(scr[14]);
    const double pr  = 1.0 / (1.0 + exp(-scr[15]));
    const uint32_t ridx = (uint32_t)mol * 32u + (uint32_t)n;
    const double uu = (double)bits_to_unit(pbits(k2p.a, k2p.b, ridx));
    const double arom = (uu < pr) ? 1.0 : 0.0;
    const double valt[10] = {4.0/5.0, 3.0/5.0, 2.0/5.0, 1.0/5.0, 4.0/5.0,
                             2.0/5.0, 6.0/5.0, 1.0/5.0, 4.0/5.0, 4.0/5.0};
    double nf[17];
    #pragma unroll
    for (int i = 0; i < 10; ++i) nf[i] = (i == asel) ? 1.0 : 0.0;
    nf[10] = deg; nf[11] = chg;
    #pragma unroll
    for (int j = 0; j < 3; ++j) nf[12 + j] = (j == hsel) ? 1.0 : 0.0;
    nf[15] = arom; nf[16] = valt[asel];

    const size_t o = ((size_t)mol * 32 + n) * 17;
    #pragma unroll
    for (int i = 0; i < 17; ++i) {
      sNF[pair][wh][n][i] = (float)nf[i];
      out[o + i] = (float)nf[i];
    }
  }

  // ---------------- phase C: lp means + edge heads for own molecule
  {
    if (ln == 62) {
      double sa = 0.0;
      for (int n = 0; n < 32; ++n) sa += sLP[pair][wh][n];
      out[2228224 + (size_t)mol] = (float)(sa / 32.0);
    } else if (ln == 63) {
      double sh = 0.0;
      for (int n = 0; n < 32; ++n) sh += sLP[pair][wh][32 + n];
      out[2232320 + (size_t)mol] = (float)(sh / 32.0);
    } else {
      const int e = ln;                       // 0..61
      const int nu_ = (e < 31) ? e : (e - 30);
      const int nv_ = (e < 31) ? (e + 1) : (e - 31);
      double lex = 0.0;
      double lt[4] = {0.0, 0.0, 0.0, 0.0};
      for (int i = 0; i < 17; ++i) {
        const double f = (double)sNF[pair][wh][nu_][i];
        lex = fma(f, (double)w_eex[i], lex);
        #pragma unroll
        for (int c = 0; c < 4; ++c) lt[c] = fma(f, (double)w_ety[i * 4 + c], lt[c]);
      }
      for (int i = 0; i < 17; ++i) {
        const double f = (double)sNF[pair][wh][nv_][i];
        lex = fma(f, (double)w_eex[17 + i], lex);
        #pragma unroll
        for (int c = 0; c < 4; ++c) lt[c] = fma(f, (double)w_ety[(17 + i) * 4 + c], lt[c]);
      }
      lex += (double)b_eex[0];
      #pragma unroll
      for (int c = 0; c < 4; ++c) lt[c] += (double)b_ety[c];

      const double pex = 1.0 / (1.0 + exp(-lex));
      out[3252224 + (size_t)mol * 62 + e] = (pex > 0.5) ? 1.f : 0.f;

      const uint32_t tbase = ((uint32_t)mol * 62u + (uint32_t)e) * 4u;
      int tsel = 0; double tbest = 0.0;
      #pragma unroll
      for (int c = 0; c < 4; ++c) {
        const double g = (double)jgumbel(k3p.a, k3p.b, tbase + (uint32_t)c);
        const double sc = lt[c] + g;
        if (c == 0 || sc > tbest) { tbest = sc; tsel = c; }
      }
      const size_t o = 2236416 + ((size_t)mol * 62 + e) * 4;
      #pragma unroll
      for (int c = 0; c < 4; ++c) out[o + c] = (c == tsel) ? 1.f : 0.f;
    }
  }
}

extern "C" void kernel_launch(void* const* d_in, const int* in_sizes, int n_in,
                              void* d_out, int out_size, void* d_ws, size_t ws_size,
                              hipStream_t stream) {
  (void)in_sizes; (void)n_in; (void)out_size; (void)d_ws; (void)ws_size;
  hipLaunchKernelGGL(gen_kernel, dim3(1024), dim3(256), 0, stream,
                     (const float*)d_in[0],  (const float*)d_in[1],
                     (const float*)d_in[2],  (const float*)d_in[3],
                     (const float*)d_in[4],  (const float*)d_in[5],
                     (const float*)d_in[6],  (const float*)d_in[7],
                     (const float*)d_in[8],  (const float*)d_in[9],
                     (const float*)d_in[10], (const float*)d_in[11],
                     (const float*)d_in[12], (const float*)d_in[13],
                     (const float*)d_in[14], (const float*)d_in[15],
                     (const float*)d_in[16], (const float*)d_in[17],
                     (const float*)d_in[18], (const float*)d_in[19],
                     (const float*)d_in[20], (float*)d_out);
}